// Round 17
// baseline (93.284 us; speedup 1.0000x reference)
//
#include <hip/hip_runtime.h>
#include <hip/hip_bf16.h>

// Ball query: for each (b, p) center, collect first S point indices n with
// ||xyz[b,n] - center[b,p]||^2 < r^2 (index order), zero-fill the rest.
//
// FROZEN FP arithmetic (R6, bit-matches harness "np" ref = XLA w/ contraction):
//   cn = fma(cz,cz, fma(cy,cy, cx*cx))          (contracted mul+reduce)
//   xn = fma(z,z,   fma(y,y,   x*x))            (precomputed in pack kernel;
//                                                fp32 store/reload bit-exact)
//   dot= fma(cz,z,  fma(cy,y,  cx*x))           (ascending-K FMA)
//   d2 = (cn + xn) - 2*dot ;  valid = d2 < r*r  (all fp32, strict <)
// DO NOT reorder/refactor these ops — a rounding change flips boundary masks.
//
// R17 = R16 resubmitted (R16 hit GPUAcquisitionTimeout, no data).
// INSTRUMENTED PROBE: seven structures (R6-R15) all plateau at kernel
// ~37-44us while every single-resource model predicts 5-20us; the kernel has
// been invisible to rocprof since R7 (below the 40us fill-dispatch cutoff).
// This round doubles the grid (c = blockIdx.x & 16383; both halves write
// identical values — benign same-value race on aligned int stores) so the
// ~76us dispatch lands top-1 WITH counters. Headline regresses this round;
// next round reverts to the best structure armed with VALUBusy/Occupancy
// evidence. Inner structure = R15 verbatim (best so far, 81.1us headline).

typedef float f32x4 __attribute__((ext_vector_type(4)));

__global__ __launch_bounds__(256) void pack_points(
    const float* __restrict__ xyz,   // [B*N, 3]
    f32x4* __restrict__ q,           // [B*N] packed {x,y,z,xn}
    int total)
{
    const int n = blockIdx.x * blockDim.x + threadIdx.x;
    if (n >= total) return;
    const float x = xyz[(size_t)n * 3 + 0];
    const float y = xyz[(size_t)n * 3 + 1];
    const float z = xyz[(size_t)n * 3 + 2];
    // FROZEN xn sequence:
    const float xn = __builtin_fmaf(z, z,
                      __builtin_fmaf(y, y, __fmul_rn(x, x)));
    f32x4 v;
    v[0] = x; v[1] = y; v[2] = z; v[3] = xn;
    q[n] = v;
}

__global__ __launch_bounds__(64) void ball_query_wave(
    const f32x4* __restrict__ q,          // [B*N] packed {x,y,z,xn}
    const float* __restrict__ center,     // [B, P, 3]
    const float* __restrict__ p_radius,   // [1]
    const int*   __restrict__ p_sample,   // [1]
    int* __restrict__ out,                // [B, P, S]
    int B, int N, int P, int cmask)
{
    const int S = p_sample[0];
    const float r = p_radius[0];
    const float r2 = __fmul_rn(r, r);

    // PROBE: two grid-halves compute the same centers (identical writes).
    const int c = blockIdx.x & cmask;
    const int lane = threadIdx.x;         // 0..63

    const int b = c / P;

    // Center coords + squared norm (uniform address -> broadcast)
    const float cx = center[(size_t)c * 3 + 0];
    const float cy = center[(size_t)c * 3 + 1];
    const float cz = center[(size_t)c * 3 + 2];
    // FROZEN cn sequence:
    const float cn = __builtin_fmaf(cz, cz,
                      __builtin_fmaf(cy, cy, __fmul_rn(cx, cx)));

    const f32x4* qb = q + (size_t)b * N;
    int* ob = out + (size_t)c * S;

    int cnt = 0;
    // N = 16384 = 32 batches of 512; early exit at 512 granularity.
    for (int n0 = 0; n0 < N && cnt < S; n0 += 512) {
        // Phase 1: 8 independent aligned dwordx4 loads — all in flight.
        f32x4 v[8];
#pragma unroll
        for (int j = 0; j < 8; ++j) {
            v[j] = qb[n0 + j * 64 + lane];
        }

        // Phase 2: 8 ballot phases in ascending chunk order.
#pragma unroll
        for (int j = 0; j < 8; ++j) {
            const float x = v[j][0], y = v[j][1], z = v[j][2];
            const float xn = v[j][3];     // FROZEN xn (precomputed, bit-exact)
            // FROZEN per-pair FP sequence:
            const float dot = __builtin_fmaf(cz, z,
                               __builtin_fmaf(cy, y, __fmul_rn(cx, x)));
            const float d2 = __fsub_rn(__fadd_rn(cn, xn), __fmul_rn(2.0f, dot));

            const bool valid = d2 < r2;
            const unsigned long long m = __ballot(valid);
            const int rank = __builtin_amdgcn_mbcnt_hi(
                (unsigned)(m >> 32),
                __builtin_amdgcn_mbcnt_lo((unsigned)m, 0u));
            if (valid && (cnt + rank) < S) {
                ob[cnt + rank] = n0 + j * 64 + lane;
            }
            cnt += __popcll(m);
        }
    }

    // Zero-fill unused slots (harness poisons d_out).
    if (cnt > S) cnt = S;
    for (int s = cnt + lane; s < S; s += 64) {
        ob[s] = 0;
    }
}

extern "C" void kernel_launch(void* const* d_in, const int* in_sizes, int n_in,
                              void* d_out, int out_size, void* d_ws, size_t ws_size,
                              hipStream_t stream) {
    const float* xyz      = (const float*)d_in[0];   // [B, N, 3]
    const float* center   = (const float*)d_in[1];   // [B, P, 3]
    const float* p_radius = (const float*)d_in[2];   // scalar
    const int*   p_sample = (const int*)d_in[3];     // scalar

    const int B = 8;
    const int N = in_sizes[0] / (B * 3);   // 16384
    const int P = in_sizes[1] / (B * 3);   // 2048

    int* out = (int*)d_out;
    f32x4* q = (f32x4*)d_ws;               // B*N*16 B = 2 MB << ws_size

    // Pass 1: pack {x,y,z,xn}
    const int total = B * N;               // 131072
    pack_points<<<(total + 255) / 256, 256, 0, stream>>>(xyz, q, total);

    // Pass 2 (PROBE): 2x grid, both halves identical -> dispatch ~76us,
    // guaranteed visible in rocprof top-5 with counters.
    const int BP = B * P;                  // 16384 (power of 2)
    ball_query_wave<<<2 * BP, 64, 0, stream>>>(
        q, center, p_radius, p_sample, out, B, N, P, BP - 1);
}

// Round 18
// 79.306 us; speedup vs baseline: 1.1763x; 1.1763x over previous
//
#include <hip/hip_runtime.h>
#include <hip/hip_bf16.h>

// Ball query: for each (b, p) center, collect first S point indices n with
// ||xyz[b,n] - center[b,p]||^2 < r^2 (index order), zero-fill the rest.
//
// FROZEN FP arithmetic (R6, bit-matches harness "np" ref = XLA w/ contraction):
//   cn = fma(cz,cz, fma(cy,cy, cx*cx))          (contracted mul+reduce)
//   xn = fma(z,z,   fma(y,y,   x*x))            (precomputed in pack kernel;
//                                                fp32 store/reload bit-exact)
//   dot= fma(cz,z,  fma(cy,y,  cx*x))           (ascending-K FMA)
//   d2 = (cn + xn) - 2*dot ;  valid = d2 < r*r  (all fp32, strict <)
// DO NOT reorder/refactor these ops — a rounding change flips boundary masks.
//
// R18: revert the R17 2x probe grid; keep R15 structure (best: 81.1us).
// Probe verdict: doubling all scan work added only 12.2us headline ->
// kernel(1x) ~15-25us vs ~52us immovable harness overhead (ws poison fill
// ~40us + restores + replay gaps). Prior neutrals (R11-R15) explained: the
// contested slice was ~20us, and throughput/instr/memory levers are all
// non-binding. New this round: XCD-affine swizzle — c = (blockIdx&7)*P +
// (blockIdx>>3) maps each of the 8 xyz slabs to one XCD (slab = 256 KB fits
// its 4 MB L2), removing cross-XCD L2 churn on first touch. Zero structural
// risk; speed-only heuristic.
// NO global atomics (R9: 7x regression).

typedef float f32x4 __attribute__((ext_vector_type(4)));

__global__ __launch_bounds__(256) void pack_points(
    const float* __restrict__ xyz,   // [B*N, 3]
    f32x4* __restrict__ q,           // [B*N] packed {x,y,z,xn}
    int total)
{
    const int n = blockIdx.x * blockDim.x + threadIdx.x;
    if (n >= total) return;
    const float x = xyz[(size_t)n * 3 + 0];
    const float y = xyz[(size_t)n * 3 + 1];
    const float z = xyz[(size_t)n * 3 + 2];
    // FROZEN xn sequence:
    const float xn = __builtin_fmaf(z, z,
                      __builtin_fmaf(y, y, __fmul_rn(x, x)));
    f32x4 v;
    v[0] = x; v[1] = y; v[2] = z; v[3] = xn;
    q[n] = v;
}

__global__ __launch_bounds__(64) void ball_query_wave(
    const f32x4* __restrict__ q,          // [B*N] packed {x,y,z,xn}
    const float* __restrict__ center,     // [B, P, 3]
    const float* __restrict__ p_radius,   // [1]
    const int*   __restrict__ p_sample,   // [1]
    int* __restrict__ out,                // [B, P, S]
    int B, int N, int P)
{
    const int S = p_sample[0];
    const float r = p_radius[0];
    const float r2 = __fmul_rn(r, r);

    // XCD-affine swizzle: consecutive blockIdx round-robin across XCDs, so
    // (blockIdx & 7) selects the batch slab -> XCD x streams only slab x.
    const int c = (blockIdx.x & 7) * P + (blockIdx.x >> 3);
    const int lane = threadIdx.x;         // 0..63

    const int b = c / P;                  // == blockIdx.x & 7

    // Center coords + squared norm (uniform address -> broadcast)
    const float cx = center[(size_t)c * 3 + 0];
    const float cy = center[(size_t)c * 3 + 1];
    const float cz = center[(size_t)c * 3 + 2];
    // FROZEN cn sequence:
    const float cn = __builtin_fmaf(cz, cz,
                      __builtin_fmaf(cy, cy, __fmul_rn(cx, cx)));

    const f32x4* qb = q + (size_t)b * N;
    int* ob = out + (size_t)c * S;

    int cnt = 0;
    // N = 16384 = 32 batches of 512; early exit at 512 granularity.
    for (int n0 = 0; n0 < N && cnt < S; n0 += 512) {
        // Phase 1: 8 independent aligned dwordx4 loads — all in flight.
        f32x4 v[8];
#pragma unroll
        for (int j = 0; j < 8; ++j) {
            v[j] = qb[n0 + j * 64 + lane];
        }

        // Phase 2: 8 ballot phases in ascending chunk order.
#pragma unroll
        for (int j = 0; j < 8; ++j) {
            const float x = v[j][0], y = v[j][1], z = v[j][2];
            const float xn = v[j][3];     // FROZEN xn (precomputed, bit-exact)
            // FROZEN per-pair FP sequence:
            const float dot = __builtin_fmaf(cz, z,
                               __builtin_fmaf(cy, y, __fmul_rn(cx, x)));
            const float d2 = __fsub_rn(__fadd_rn(cn, xn), __fmul_rn(2.0f, dot));

            const bool valid = d2 < r2;
            const unsigned long long m = __ballot(valid);
            const int rank = __builtin_amdgcn_mbcnt_hi(
                (unsigned)(m >> 32),
                __builtin_amdgcn_mbcnt_lo((unsigned)m, 0u));
            if (valid && (cnt + rank) < S) {
                ob[cnt + rank] = n0 + j * 64 + lane;
            }
            cnt += __popcll(m);
        }
    }

    // Zero-fill unused slots (harness poisons d_out).
    if (cnt > S) cnt = S;
    for (int s = cnt + lane; s < S; s += 64) {
        ob[s] = 0;
    }
}

extern "C" void kernel_launch(void* const* d_in, const int* in_sizes, int n_in,
                              void* d_out, int out_size, void* d_ws, size_t ws_size,
                              hipStream_t stream) {
    const float* xyz      = (const float*)d_in[0];   // [B, N, 3]
    const float* center   = (const float*)d_in[1];   // [B, P, 3]
    const float* p_radius = (const float*)d_in[2];   // scalar
    const int*   p_sample = (const int*)d_in[3];     // scalar

    const int B = 8;
    const int N = in_sizes[0] / (B * 3);   // 16384
    const int P = in_sizes[1] / (B * 3);   // 2048

    int* out = (int*)d_out;
    f32x4* q = (f32x4*)d_ws;               // B*N*16 B = 2 MB << ws_size

    // Pass 1: pack {x,y,z,xn}
    const int total = B * N;               // 131072
    pack_points<<<(total + 255) / 256, 256, 0, stream>>>(xyz, q, total);

    // Pass 2: one wave (own 64-thread block) per center, XCD-affine swizzle.
    const int blocks = B * P;              // 16384
    ball_query_wave<<<blocks, 64, 0, stream>>>(
        q, center, p_radius, p_sample, out, B, N, P);
}